// Round 4
// baseline (564.811 us; speedup 1.0000x reference)
//
#include <hip/hip_runtime.h>
#include <hip/hip_bf16.h>
#include <math.h>

#define NN 50000
#define EE 800000
#define RNA_D 645
#define KFUSE 651
#define KPACK 704
#define HD 128
#define GG 200
#define SAK 72    // LDS k-stride (bf16): 64+8 pad
#define HGS 136   // persistent LDS row stride (bf16)

typedef __attribute__((ext_vector_type(8))) short shortx8;
typedef __attribute__((ext_vector_type(4))) short shortx4;
typedef __attribute__((ext_vector_type(4))) float floatx4;

__device__ __forceinline__ float lrelu(float x){ return x >= 0.f ? x : 0.2f*x; }
__device__ __forceinline__ short f2bf(float x){
  union { __hip_bfloat16 h; short s; } u; u.h = __float2bfloat16(x); return u.s;
}
__device__ __forceinline__ float bf2f(short s){
  union { float f; unsigned u; } c; c.u = ((unsigned)(unsigned short)s) << 16; return c.f;
}
__device__ __forceinline__ float2 upk(unsigned u){
  union { float f; unsigned v; } a, b;
  a.v = u << 16; b.v = u & 0xffff0000u;
  return make_float2(a.f, b.f);
}

// ---------------- graph prep ----------------
__global__ void hist_gstart_kernel(const int* __restrict__ dst, int* __restrict__ deg,
                                   const int* __restrict__ batch, int* __restrict__ gstart){
  int e = blockIdx.x*256 + threadIdx.x;
  if (e < EE) atomicAdd(&deg[dst[e]], 1);
  if (e < NN){
    int g = batch[e];
    if (e == 0){ for (int gg=0; gg<=g; ++gg) gstart[gg] = 0; }
    else { int gp = batch[e-1]; for (int gg=gp+1; gg<=g; ++gg) gstart[gg] = e; }
    if (e == NN-1){ for (int gg=g+1; gg<=GG; ++gg) gstart[gg] = NN; }
  }
}
__global__ void scan1_kernel(const int* __restrict__ deg, int* __restrict__ row_start,
                             int* __restrict__ blocksum){
  __shared__ int s[256];
  int i = blockIdx.x*256 + threadIdx.x;
  int v = (i < NN) ? deg[i] : 0;
  s[threadIdx.x] = v;
  __syncthreads();
  for (int off=1; off<256; off<<=1){
    int t = (threadIdx.x >= off) ? s[threadIdx.x-off] : 0;
    __syncthreads();
    s[threadIdx.x] += t;
    __syncthreads();
  }
  if (i < NN) row_start[i] = s[threadIdx.x] - v;
  if (threadIdx.x == 255) blocksum[blockIdx.x] = s[255];
}
__global__ void scan2_kernel(int* __restrict__ blocksum, int nb){
  __shared__ int s[256];
  int v = (threadIdx.x < nb) ? blocksum[threadIdx.x] : 0;
  s[threadIdx.x] = v;
  __syncthreads();
  for (int off=1; off<256; off<<=1){
    int t = (threadIdx.x >= off) ? s[threadIdx.x-off] : 0;
    __syncthreads();
    s[threadIdx.x] += t;
    __syncthreads();
  }
  blocksum[threadIdx.x] = s[threadIdx.x] - v;
}
__global__ void scan3_kernel(int* __restrict__ row_start, const int* __restrict__ blocksum,
                             int* __restrict__ cursor){
  int i = blockIdx.x*256 + threadIdx.x;
  if (i < NN){
    int v = row_start[i] + blocksum[blockIdx.x];
    row_start[i] = v;
    cursor[i] = v;
  }
  if (i == 0) row_start[NN] = EE;
}
__global__ void scatter_kernel(const int* __restrict__ srcl, const int* __restrict__ dstl,
                               int* __restrict__ cursor, int* __restrict__ csr_src){
  int e = blockIdx.x*256 + threadIdx.x;
  if (e >= EE) return;
  int d = dstl[e];
  int slot = atomicAdd(&cursor[d], 1);
  csr_src[slot] = srcl[e];
}

// ---------------- weight prep ----------------
__global__ void wprep_all_kernel(const float* __restrict__ Wf, const float* __restrict__ Wg,
                                 const float* __restrict__ Wgt, const float* __restrict__ Wh,
                                 const float* __restrict__ W1,
                                 short* __restrict__ Tf, short* __restrict__ Tg,
                                 short* __restrict__ Tgt, short* __restrict__ Th,
                                 short* __restrict__ T1){
  int idx = blockIdx.x*256 + threadIdx.x;
  const int S0=128*KPACK, S1=128*128, S2=128*256, S3=128*128, S4=64*128;
  if (idx < S0){ int n=idx/KPACK, k=idx-n*KPACK; Tf[idx]=f2bf(k<KFUSE ? Wf[k*128+n] : 0.f); return; }
  idx -= S0;
  if (idx < S1){ int n=idx>>7, k=idx&127; Tg[idx]=f2bf(Wg[k*128+n]); return; }
  idx -= S1;
  if (idx < S2){ int n=idx>>8, k=idx&255; Tgt[idx]=f2bf(Wgt[k*128+n]); return; }
  idx -= S2;
  if (idx < S3){ int n=idx>>7, k=idx&127; Th[idx]=f2bf(Wh[k*128+n]); return; }
  idx -= S3;
  if (idx < S4){ int n=idx>>7, k=idx&127; T1[idx]=f2bf(W1[k*64+n]); return; }
}

// ---------------- fused: fuse-GEMM(K=704)+LN+relu -> h, then xw-GEMM(K=128) -> xwb,es,ed
// 512 threads (8 waves x 16-row M-frags). LDS overlaid: phase1 {sA,sB1} reused as {hA} + sB2.
__launch_bounds__(512, 4)
__global__ void fuse_xw_kernel(const float* __restrict__ rna, const float* __restrict__ ss,
                               const short* __restrict__ Wtf, const float* __restrict__ bfu,
                               const float* __restrict__ g1, const float* __restrict__ b1,
                               const short* __restrict__ Wtg,
                               const float* __restrict__ as_, const float* __restrict__ ad_,
                               float* __restrict__ hout, short* __restrict__ xwb,
                               float* __restrict__ es, float* __restrict__ ed){
  __shared__ short lds[26624];          // 53248 B total
  short* sA  = lds;                     // phase1 A: 128*SAK = 9216 shorts
  short* sB1 = lds + 9216;              // phase1 B: 9216 shorts
  short* hA  = lds;                     // phase1-epilogue..phase2: 128*HGS = 17408 shorts
  short* sB2 = lds + 17408;             // phase2 B: 9216 shorts

  const int tid  = threadIdx.x;
  const int wave = tid >> 6, lane = tid & 63;
  const int quad = lane >> 4, l16 = lane & 15;
  const int rowBase = blockIdx.x * 128;
  const int ar = tid >> 2;              // staging row 0..127
  const int ac = (tid & 3) * 16;        // staging col chunk 0/16/32/48
  const int gr_ar = rowBase + ar;
  const bool okr = gr_ar < NN;

  floatx4 acc[8];
  #pragma unroll
  for (int ct=0;ct<8;++ct)
    #pragma unroll
    for (int j=0;j<4;++j) acc[ct][j] = 0.f;

  // ===== phase 1: fuse GEMM K=704 =====
  for (int k0 = 0; k0 < KPACK; k0 += 64){
    // stage A: 16 floats per thread (batched), then 2x b128 LDS writes
    {
      float fv[16];
      if (k0 < 640){
        const float* p = rna + (size_t)gr_ar*RNA_D + k0 + ac;
        #pragma unroll
        for (int j=0;j<16;++j) fv[j] = okr ? p[j] : 0.f;
      } else {
        #pragma unroll
        for (int j=0;j<16;++j){
          int c = k0 + ac + j;
          float v = 0.f;
          if (okr){
            if (c < RNA_D) v = rna[(size_t)gr_ar*RNA_D + c];
            else if (c < KFUSE) v = ss[gr_ar*6 + (c - RNA_D)];
          }
          fv[j] = v;
        }
      }
      short tb[16];
      #pragma unroll
      for (int j=0;j<16;++j) tb[j] = f2bf(fv[j]);
      *(shortx8*)&sA[ar*SAK + ac]     = *(shortx8*)&tb[0];
      *(shortx8*)&sA[ar*SAK + ac + 8] = *(shortx8*)&tb[8];
    }
    // stage B: 16 bf16 per thread
    {
      shortx8 b0 = *(const shortx8*)&Wtf[(size_t)ar*KPACK + k0 + ac];
      shortx8 b1v = *(const shortx8*)&Wtf[(size_t)ar*KPACK + k0 + ac + 8];
      *(shortx8*)&sB1[ar*SAK + ac]     = b0;
      *(shortx8*)&sB1[ar*SAK + ac + 8] = b1v;
    }
    __syncthreads();
    #pragma unroll
    for (int ks=0; ks<2; ++ks){
      int kb = ks*32 + quad*8;
      shortx8 af = *(const shortx8*)&sA[(wave*16 + l16)*SAK + kb];
      #pragma unroll
      for (int ct=0; ct<8; ++ct){
        shortx8 bf = *(const shortx8*)&sB1[(ct*16 + l16)*SAK + kb];
        acc[ct] = __builtin_amdgcn_mfma_f32_16x16x32_bf16(af, bf, acc[ct], 0,0,0);
      }
    }
    __syncthreads();
  }

  // phase-1 epilogue: +bias, LN(128), relu -> hout (fp32) and hA (bf16)
  // (sA/sB1 dead after the final barrier; hA overlays them)
  {
    float biasv[8], gv[8], bv[8];
    #pragma unroll
    for (int ct=0;ct<8;++ct){
      biasv[ct] = bfu[ct*16+l16]; gv[ct] = g1[ct*16+l16]; bv[ct] = b1[ct*16+l16];
    }
    #pragma unroll
    for (int i=0;i<4;++i){
      int row = wave*16 + quad*4 + i;
      int gr = rowBase + row;
      float v[8]; float s=0.f, q=0.f;
      #pragma unroll
      for (int ct=0;ct<8;++ct){
        v[ct] = acc[ct][i] + biasv[ct];
        s += v[ct]; q = fmaf(v[ct], v[ct], q);
      }
      #pragma unroll
      for (int off=1; off<16; off<<=1){ s += __shfl_xor(s,off); q += __shfl_xor(q,off); }
      float mean = s * (1.f/128.f);
      float inv  = rsqrtf(q*(1.f/128.f) - mean*mean + 1e-5f);
      #pragma unroll
      for (int ct=0;ct<8;++ct){
        float o = fmaxf((v[ct]-mean)*inv*gv[ct] + bv[ct], 0.f);
        if (gr < NN) hout[(size_t)gr*HD + ct*16 + l16] = o;
        hA[row*HGS + ct*16 + l16] = f2bf(o);
      }
    }
  }
  __syncthreads();

  // ===== phase 2: xw GEMM K=128, A=hA =====
  floatx4 acc2[8];
  #pragma unroll
  for (int ct=0;ct<8;++ct)
    #pragma unroll
    for (int j=0;j<4;++j) acc2[ct][j] = 0.f;

  for (int c2=0; c2<2; ++c2){
    {
      shortx8 b0 = *(const shortx8*)&Wtg[(size_t)ar*HD + c2*64 + ac];
      shortx8 b1v = *(const shortx8*)&Wtg[(size_t)ar*HD + c2*64 + ac + 8];
      *(shortx8*)&sB2[ar*SAK + ac]     = b0;
      *(shortx8*)&sB2[ar*SAK + ac + 8] = b1v;
    }
    __syncthreads();
    #pragma unroll
    for (int ks=0; ks<2; ++ks){
      int kg = c2*64 + ks*32 + quad*8;
      int kk = ks*32 + quad*8;
      shortx8 af = *(const shortx8*)&hA[(wave*16 + l16)*HGS + kg];
      #pragma unroll
      for (int ct=0; ct<8; ++ct){
        shortx8 bf = *(const shortx8*)&sB2[(ct*16 + l16)*SAK + kk];
        acc2[ct] = __builtin_amdgcn_mfma_f32_16x16x32_bf16(af, bf, acc2[ct], 0,0,0);
      }
    }
    __syncthreads();
  }

  // phase-2 epilogue: store xwb bf16 + es/ed
  {
    float asv[8], adv[8];
    #pragma unroll
    for (int ct=0;ct<8;++ct){ asv[ct] = as_[ct*16+l16]; adv[ct] = ad_[ct*16+l16]; }
    #pragma unroll
    for (int i=0;i<4;++i){
      int gr = rowBase + wave*16 + quad*4 + i;
      float s=0.f, d=0.f;
      #pragma unroll
      for (int ct=0;ct<8;++ct){
        float v = acc2[ct][i];
        s = fmaf(v, asv[ct], s); d = fmaf(v, adv[ct], d);
        if (gr < NN) xwb[(size_t)gr*HD + ct*16 + l16] = f2bf(v);
      }
      #pragma unroll
      for (int off=1; off<16; off<<=1){ s += __shfl_xor(s,off); d += __shfl_xor(d,off); }
      if (l16 == 0 && gr < NN){ es[gr] = s; ed[gr] = d; }
    }
  }
}

// ---------------- MFMA GEMM (layer-2 xw with fused graphnorm A-staging), 512 threads --------
template<bool GNA>
__launch_bounds__(512, 4)
__global__ void mfma_gemm(const float* __restrict__ A0,
                          const short* __restrict__ Wt,
                          const float* __restrict__ gb,
                          const float* __restrict__ as_, const float* __restrict__ ad_,
                          const int* __restrict__ batch, const float* __restrict__ gnsh,
                          const float* __restrict__ gnsc, float* __restrict__ side,
                          short* __restrict__ outb,
                          float* __restrict__ es, float* __restrict__ ed,
                          int K, int Kp){
  __shared__ short sA[128*SAK];
  __shared__ short sB[128*SAK];
  const int tid  = threadIdx.x;
  const int wave = tid >> 6, lane = tid & 63;
  const int quad = lane >> 4, l16 = lane & 15;
  const int rowBase = blockIdx.x * 128;
  const int ar = tid >> 2;
  const int ac = (tid & 3) * 16;
  const int gr_ar = rowBase + ar;
  const bool okr = gr_ar < NN;

  floatx4 acc[8];
  #pragma unroll
  for (int ct=0;ct<8;++ct)
    #pragma unroll
    for (int j=0;j<4;++j) acc[ct][j] = 0.f;

  for (int k0 = 0; k0 < K; k0 += 64){
    // ---- stage A: 4x float4 per thread ----
    {
      float4 fv[4];
      #pragma unroll
      for (int q=0;q<4;++q)
        fv[q] = okr ? *(const float4*)&A0[(size_t)gr_ar*HD + k0 + ac + q*4]
                    : make_float4(0.f,0.f,0.f,0.f);
      if (GNA){
        if (okr){
          int g = batch[gr_ar];
          #pragma unroll
          for (int q=0;q<4;++q){
            int cb = k0 + ac + q*4;
            float4 sh = *(const float4*)&gnsh[g*HD + cb];
            float4 sc = *(const float4*)&gnsc[g*HD + cb];
            float4 bb = *(const float4*)&gb[cb];
            float4 v;
            v.x = fmaxf((fv[q].x - sh.x)*sc.x + bb.x, 0.f);
            v.y = fmaxf((fv[q].y - sh.y)*sc.y + bb.y, 0.f);
            v.z = fmaxf((fv[q].z - sh.z)*sc.z + bb.z, 0.f);
            v.w = fmaxf((fv[q].w - sh.w)*sc.w + bb.w, 0.f);
            *(float4*)&side[(size_t)gr_ar*HD + cb] = v;
            fv[q] = v;
          }
        }
      }
      short tb[16];
      #pragma unroll
      for (int q=0;q<4;++q){
        tb[q*4+0]=f2bf(fv[q].x); tb[q*4+1]=f2bf(fv[q].y);
        tb[q*4+2]=f2bf(fv[q].z); tb[q*4+3]=f2bf(fv[q].w);
      }
      *(shortx8*)&sA[ar*SAK + ac]     = *(shortx8*)&tb[0];
      *(shortx8*)&sA[ar*SAK + ac + 8] = *(shortx8*)&tb[8];
    }
    // ---- stage B ----
    {
      shortx8 b0 = *(const shortx8*)&Wt[(size_t)ar*Kp + k0 + ac];
      shortx8 b1v = *(const shortx8*)&Wt[(size_t)ar*Kp + k0 + ac + 8];
      *(shortx8*)&sB[ar*SAK + ac]     = b0;
      *(shortx8*)&sB[ar*SAK + ac + 8] = b1v;
    }
    __syncthreads();
    // ---- MFMA ----
    #pragma unroll
    for (int ks=0; ks<2; ++ks){
      int kb = ks*32 + quad*8;
      shortx8 af = *(const shortx8*)&sA[(wave*16 + l16)*SAK + kb];
      #pragma unroll
      for (int ct=0; ct<8; ++ct){
        shortx8 bf = *(const shortx8*)&sB[(ct*16 + l16)*SAK + kb];
        acc[ct] = __builtin_amdgcn_mfma_f32_16x16x32_bf16(af, bf, acc[ct], 0,0,0);
      }
    }
    __syncthreads();
  }

  // ---- epilogue: xw + es/ed ----
  {
    float asv[8], adv[8];
    #pragma unroll
    for (int ct=0;ct<8;++ct){ asv[ct] = as_[ct*16+l16]; adv[ct] = ad_[ct*16+l16]; }
    #pragma unroll
    for (int i=0;i<4;++i){
      int gr = rowBase + wave*16 + quad*4 + i;
      float s=0.f, d=0.f;
      #pragma unroll
      for (int ct=0;ct<8;++ct){
        float v = acc[ct][i];
        s = fmaf(v, asv[ct], s); d = fmaf(v, adv[ct], d);
        if (gr < NN) outb[(size_t)gr*HD + ct*16 + l16] = f2bf(v);
      }
      #pragma unroll
      for (int off=1; off<16; off<<=1){ s += __shfl_xor(s,off); d += __shfl_xor(d,off); }
      if (l16 == 0 && gr < NN){ es[gr] = s; ed[gr] = d; }
    }
  }
}

// ---------------- GAT aggregation: bf16 gather ----------------
__launch_bounds__(256)
__global__ void gat_aggregate_kernel(const short* __restrict__ xwb, const float* __restrict__ es,
                                     const float* __restrict__ ed, const int* __restrict__ row_start,
                                     const int* __restrict__ csr_src, const float* __restrict__ bgat,
                                     float* __restrict__ out){
  int gid = blockIdx.x*256 + threadIdx.x;
  int n = gid >> 6, lane = gid & 63;
  if (n >= NN) return;
  int beg = row_start[n], end = row_start[n+1];
  float edn = ed[n];
  float sc_self = lrelu(es[n] + edn);

  int i0 = beg + lane;
  bool v0 = i0 < end;
  int sA = v0 ? csr_src[i0] : 0;
  float eA = v0 ? lrelu(es[sA] + edn) : -3.0e38f;
  float m = fmaxf(sc_self, eA);
  for (int i = beg + 64 + lane; i < end; i += 64)
    m = fmaxf(m, lrelu(es[csr_src[i]] + edn));
  #pragma unroll
  for (int off=1; off<64; off<<=1) m = fmaxf(m, __shfl_xor(m, off));

  float wA = v0 ? __expf(eA - m) : 0.f;
  float wsum_l = wA;
  float wself = __expf(sc_self - m);
  float2 self2 = upk(*(const unsigned*)&xwb[(size_t)n*HD + 2*lane]);
  float a0 = wself*self2.x, a1 = wself*self2.y;

  int deg0 = min(end - beg, 64);
  int j = 0;
  for (; j + 8 <= deg0; j += 8){
    int ss[8]; float ww[8]; unsigned xv[8];
    #pragma unroll
    for (int u=0;u<8;++u){ ss[u]=__shfl(sA,j+u); ww[u]=__shfl(wA,j+u); }
    #pragma unroll
    for (int u=0;u<8;++u) xv[u] = *(const unsigned*)&xwb[(size_t)ss[u]*HD + 2*lane];
    #pragma unroll
    for (int u=0;u<8;++u){ float2 f=upk(xv[u]); a0=fmaf(ww[u],f.x,a0); a1=fmaf(ww[u],f.y,a1); }
  }
  for (; j < deg0; ++j){
    int s=__shfl(sA,j); float w=__shfl(wA,j);
    float2 f = upk(*(const unsigned*)&xwb[(size_t)s*HD + 2*lane]);
    a0=fmaf(w,f.x,a0); a1=fmaf(w,f.y,a1);
  }
  for (int c = beg + 64; c < end; c += 64){
    int i = c + lane;
    bool vb = i < end;
    int sB = vb ? csr_src[i] : 0;
    float wB = vb ? __expf(lrelu(es[sB] + edn) - m) : 0.f;
    wsum_l += wB;
    int degc = min(end - c, 64);
    for (int jj=0; jj<degc; ++jj){
      int s=__shfl(sB,jj); float w=__shfl(wB,jj);
      float2 f = upk(*(const unsigned*)&xwb[(size_t)s*HD + 2*lane]);
      a0=fmaf(w,f.x,a0); a1=fmaf(w,f.y,a1);
    }
  }
  #pragma unroll
  for (int off=1; off<64; off<<=1) wsum_l += __shfl_xor(wsum_l, off);
  float dinv = 1.f/(wsum_l + wself + 1e-16f);
  float2 b2 = *(const float2*)&bgat[2*lane];
  float2 o; o.x = a0*dinv + b2.x; o.y = a1*dinv + b2.y;
  *(float2*)&out[(size_t)n*HD + 2*lane] = o;
}

// ---------------- GraphNorm group stats ----------------
__launch_bounds__(1024)
__global__ void gn_group_kernel(const float* __restrict__ x, const int* __restrict__ gstart,
                                const float* __restrict__ gnw, const float* __restrict__ gnms,
                                float* __restrict__ shiftv, float* __restrict__ scalev){
  int g = blockIdx.x;
  int n0 = gstart[g], n1 = gstart[g+1];
  int f = threadIdx.x & 127, slot = threadIdx.x >> 7;   // 0..7
  float s = 0.f, q = 0.f;
  for (int n = n0 + slot; n < n1; n += 8){
    float v = x[(size_t)n*HD + f];
    s += v; q = fmaf(v, v, q);
  }
  __shared__ float rs[1024], rq[1024];
  rs[threadIdx.x] = s; rq[threadIdx.x] = q;
  __syncthreads();
  if (threadIdx.x < 512){ rs[threadIdx.x] += rs[threadIdx.x+512]; rq[threadIdx.x] += rq[threadIdx.x+512]; }
  __syncthreads();
  if (threadIdx.x < 256){ rs[threadIdx.x] += rs[threadIdx.x+256]; rq[threadIdx.x] += rq[threadIdx.x+256]; }
  __syncthreads();
  if (threadIdx.x < 128){
    s = rs[threadIdx.x] + rs[threadIdx.x+128];
    q = rq[threadIdx.x] + rq[threadIdx.x+128];
    float c = fmaxf((float)(n1 - n0), 1.f);
    float mean = s / c;
    float ms = gnms[f];
    float var = q/c - mean*mean*ms*(2.f - ms);
    shiftv[g*HD+f] = ms*mean;
    scalev[g*HD+f] = gnw[f] / sqrtf(var + 1e-5f);
  }
}

// ---------------- tail: gate + head(+LN2) + fc1(+LN3) + fc2, 512 threads ----------------
__launch_bounds__(512, 4)
__global__ void tail_kernel(const float* __restrict__ h1, const float* __restrict__ y2,
                            const float* __restrict__ hres, const int* __restrict__ batch,
                            const float* __restrict__ gnsh, const float* __restrict__ gnsc,
                            const float* __restrict__ gnb,
                            const short* __restrict__ Wt_gate, const float* __restrict__ b_gate,
                            const short* __restrict__ Wt_head, const float* __restrict__ b_head,
                            const float* __restrict__ ln2g, const float* __restrict__ ln2b,
                            const short* __restrict__ Wt_fc1, const float* __restrict__ b_fc1,
                            const float* __restrict__ ln3g, const float* __restrict__ ln3b,
                            const float* __restrict__ W_fc2, const float* __restrict__ b_fc2,
                            float* __restrict__ outp){
  __shared__ short hgL[128*HGS];   // persistent: h2 -> hg -> t1
  __shared__ short sA[128*SAK];
  __shared__ short sB[128*SAK];
  const int tid = threadIdx.x, wave = tid>>6, lane = tid&63;
  const int quad = lane>>4, l16 = lane&15;
  const int rowBase = blockIdx.x*128;
  const int ar = tid >> 2;
  const int ac = (tid & 3) * 16;
  const int gr_ar = rowBase + ar;
  const bool okr = gr_ar < NN;

  // ===== stage 1: gate GEMM, K=256 (A = [h1 | h2=gn(y2)+hres]) =====
  floatx4 acc[8];
  #pragma unroll
  for (int ct=0;ct<8;++ct)
    #pragma unroll
    for (int j=0;j<4;++j) acc[ct][j]=0.f;

  for (int c2=0; c2<4; ++c2){
    int kb = c2*64;
    if (kb < 128){
      float4 fv[4];
      #pragma unroll
      for (int q=0;q<4;++q)
        fv[q] = okr ? *(const float4*)&h1[(size_t)gr_ar*HD + kb + ac + q*4]
                    : make_float4(0.f,0.f,0.f,0.f);
      short tb[16];
      #pragma unroll
      for (int q=0;q<4;++q){
        tb[q*4+0]=f2bf(fv[q].x); tb[q*4+1]=f2bf(fv[q].y);
        tb[q*4+2]=f2bf(fv[q].z); tb[q*4+3]=f2bf(fv[q].w);
      }
      *(shortx8*)&sA[ar*SAK + ac]     = *(shortx8*)&tb[0];
      *(shortx8*)&sA[ar*SAK + ac + 8] = *(shortx8*)&tb[8];
    } else {
      int cb = kb - 128 + ac;
      float4 fv[4];
      if (okr){
        int g = batch[gr_ar];
        #pragma unroll
        for (int q=0;q<4;++q){
          int c = cb + q*4;
          float4 yv = *(const float4*)&y2[(size_t)gr_ar*HD + c];
          float4 hv = *(const float4*)&hres[(size_t)gr_ar*HD + c];
          float4 sh = *(const float4*)&gnsh[g*HD + c];
          float4 sc = *(const float4*)&gnsc[g*HD + c];
          float4 bb = *(const float4*)&gnb[c];
          float4 v;
          v.x = fmaxf((yv.x - sh.x)*sc.x + bb.x, 0.f) + hv.x;
          v.y = fmaxf((yv.y - sh.y)*sc.y + bb.y, 0.f) + hv.y;
          v.z = fmaxf((yv.z - sh.z)*sc.z + bb.z, 0.f) + hv.z;
          v.w = fmaxf((yv.w - sh.w)*sc.w + bb.w, 0.f) + hv.w;
          fv[q] = v;
        }
      } else {
        #pragma unroll
        for (int q=0;q<4;++q) fv[q] = make_float4(0.f,0.f,0.f,0.f);
      }
      short tb[16];
      #pragma unroll
      for (int q=0;q<4;++q){
        tb[q*4+0]=f2bf(fv[q].x); tb[q*4+1]=f2bf(fv[q].y);
        tb[q*4+2]=f2bf(fv[q].z); tb[q*4+3]=f2bf(fv[q].w);
      }
      // persist h2
      *(shortx8*)&hgL[ar*HGS + cb]     = *(shortx8*)&tb[0];
      *(shortx8*)&hgL[ar*HGS + cb + 8] = *(shortx8*)&tb[8];
      *(shortx8*)&sA[ar*SAK + ac]      = *(shortx8*)&tb[0];
      *(shortx8*)&sA[ar*SAK + ac + 8]  = *(shortx8*)&tb[8];
    }
    // stage B (Wt_gate: [128][256])
    {
      shortx8 b0 = *(const shortx8*)&Wt_gate[(size_t)ar*256 + kb + ac];
      shortx8 b1v = *(const shortx8*)&Wt_gate[(size_t)ar*256 + kb + ac + 8];
      *(shortx8*)&sB[ar*SAK + ac]     = b0;
      *(shortx8*)&sB[ar*SAK + ac + 8] = b1v;
    }
    __syncthreads();
    #pragma unroll
    for (int ks=0; ks<2; ++ks){
      int kk = ks*32 + quad*8;
      shortx8 af = *(const shortx8*)&sA[(wave*16 + l16)*SAK + kk];
      #pragma unroll
      for (int ct=0; ct<8; ++ct){
        shortx8 bf = *(const shortx8*)&sB[(ct*16 + l16)*SAK + kk];
        acc[ct] = __builtin_amdgcn_mfma_f32_16x16x32_bf16(af, bf, acc[ct], 0,0,0);
      }
    }
    __syncthreads();
  }
  // gate epilogue: hg = g*h1 + (1-g)*h2  -> hgL
  {
    float biasv[8];
    #pragma unroll
    for (int ct=0;ct<8;++ct) biasv[ct] = b_gate[ct*16+l16];
    #pragma unroll
    for (int i=0;i<4;++i){
      int row = wave*16 + quad*4 + i;
      int gr = rowBase + row;
      #pragma unroll
      for (int ct=0;ct<8;++ct){
        int c = ct*16 + l16;
        float g = 1.f/(1.f + __expf(-(acc[ct][i] + biasv[ct])));
        float x1 = (gr < NN) ? h1[(size_t)gr*HD + c] : 0.f;
        float x2 = bf2f(hgL[row*HGS + c]);
        hgL[row*HGS + c] = f2bf(g*x1 + (1.f-g)*x2);
      }
    }
  }
  __syncthreads();

  // ===== stage 2: head GEMM K=128, A=hgL, +bias LN(128) relu -> hgL =====
  floatx4 acc2[8];
  #pragma unroll
  for (int ct=0;ct<8;++ct)
    #pragma unroll
    for (int j=0;j<4;++j) acc2[ct][j]=0.f;
  for (int c2=0;c2<2;++c2){
    {
      shortx8 b0 = *(const shortx8*)&Wt_head[(size_t)ar*128 + c2*64 + ac];
      shortx8 b1v = *(const shortx8*)&Wt_head[(size_t)ar*128 + c2*64 + ac + 8];
      *(shortx8*)&sB[ar*SAK + ac]     = b0;
      *(shortx8*)&sB[ar*SAK + ac + 8] = b1v;
    }
    __syncthreads();
    #pragma unroll
    for (int ks=0; ks<2; ++ks){
      int kg = c2*64 + ks*32 + quad*8;
      int kk = ks*32 + quad*8;
      shortx8 af = *(const shortx8*)&hgL[(wave*16 + l16)*HGS + kg];
      #pragma unroll
      for (int ct=0; ct<8; ++ct){
        shortx8 bf = *(const shortx8*)&sB[(ct*16 + l16)*SAK + kk];
        acc2[ct] = __builtin_amdgcn_mfma_f32_16x16x32_bf16(af, bf, acc2[ct], 0,0,0);
      }
    }
    __syncthreads();
  }
  // head epilogue: LN(128) relu -> hgL (t1, bf16)
  {
    float biasv[8], gv[8], bv[8];
    #pragma unroll
    for (int ct=0;ct<8;++ct){
      biasv[ct] = b_head[ct*16+l16]; gv[ct] = ln2g[ct*16+l16]; bv[ct] = ln2b[ct*16+l16];
    }
    #pragma unroll
    for (int i=0;i<4;++i){
      int row = wave*16 + quad*4 + i;
      float v[8]; float s=0.f, q=0.f;
      #pragma unroll
      for (int ct=0;ct<8;++ct){
        v[ct] = acc2[ct][i] + biasv[ct];
        s += v[ct]; q = fmaf(v[ct], v[ct], q);
      }
      #pragma unroll
      for (int off=1; off<16; off<<=1){ s += __shfl_xor(s,off); q += __shfl_xor(q,off); }
      float mean = s * (1.f/128.f);
      float inv  = rsqrtf(q*(1.f/128.f) - mean*mean + 1e-5f);
      #pragma unroll
      for (int ct=0;ct<8;++ct)
        hgL[row*HGS + ct*16 + l16] = f2bf(fmaxf((v[ct]-mean)*inv*gv[ct] + bv[ct], 0.f));
    }
  }
  __syncthreads();

  // ===== stage 3: fc1 K=128 -> 64 cols, LN(64), relu, dot W_fc2 -> outp =====
  floatx4 acc3[4];
  #pragma unroll
  for (int ct=0;ct<4;++ct)
    #pragma unroll
    for (int j=0;j<4;++j) acc3[ct][j]=0.f;
  for (int c2=0;c2<2;++c2){
    {
      int n = tid >> 3;          // 0..63
      int kc = (tid & 7) * 8;    // 0..56
      *(shortx8*)&sB[n*SAK + kc] = *(const shortx8*)&Wt_fc1[(size_t)n*128 + c2*64 + kc];
    }
    __syncthreads();
    #pragma unroll
    for (int ks=0; ks<2; ++ks){
      int kg = c2*64 + ks*32 + quad*8;
      int kk = ks*32 + quad*8;
      shortx8 af = *(const shortx8*)&hgL[(wave*16 + l16)*HGS + kg];
      #pragma unroll
      for (int ct=0; ct<4; ++ct){
        shortx8 bf = *(const shortx8*)&sB[(ct*16 + l16)*SAK + kk];
        acc3[ct] = __builtin_amdgcn_mfma_f32_16x16x32_bf16(af, bf, acc3[ct], 0,0,0);
      }
    }
    __syncthreads();
  }
  {
    float biasv[4], gv[4], bv[4], w2v[4];
    #pragma unroll
    for (int ct=0;ct<4;++ct){
      biasv[ct] = b_fc1[ct*16+l16]; gv[ct] = ln3g[ct*16+l16]; bv[ct] = ln3b[ct*16+l16];
      w2v[ct] = W_fc2[ct*16+l16];
    }
    float b2 = b_fc2[0];
    #pragma unroll
    for (int i=0;i<4;++i){
      int gr = rowBase + wave*16 + quad*4 + i;
      float v[4]; float s=0.f, q=0.f;
      #pragma unroll
      for (int ct=0;ct<4;++ct){
        v[ct] = acc3[ct][i] + biasv[ct];
        s += v[ct]; q = fmaf(v[ct], v[ct], q);
      }
      #pragma unroll
      for (int off=1; off<16; off<<=1){ s += __shfl_xor(s,off); q += __shfl_xor(q,off); }
      float mean = s * (1.f/64.f);
      float inv  = rsqrtf(q*(1.f/64.f) - mean*mean + 1e-5f);
      float p = 0.f;
      #pragma unroll
      for (int ct=0;ct<4;++ct){
        float o = fmaxf((v[ct]-mean)*inv*gv[ct] + bv[ct], 0.f);
        p = fmaf(o, w2v[ct], p);
      }
      #pragma unroll
      for (int off=1; off<16; off<<=1) p += __shfl_xor(p, off);
      if (l16 == 0 && gr < NN) outp[gr] = p + b2;
    }
  }
}

// ---------------- launch ----------------
extern "C" void kernel_launch(void* const* d_in, const int* in_sizes, int n_in,
                              void* d_out, int out_size, void* d_ws, size_t ws_size,
                              hipStream_t stream){
  const float* rna    = (const float*)d_in[0];
  const float* ss     = (const float*)d_in[1];
  const int*   eidx   = (const int*)d_in[2];
  const int*   batch  = (const int*)d_in[3];
  const float* W_fuse = (const float*)d_in[4];
  const float* b_fuse = (const float*)d_in[5];
  const float* ln1_g  = (const float*)d_in[6];
  const float* ln1_b  = (const float*)d_in[7];
  const float* W_gat  = (const float*)d_in[8];
  const float* att_src= (const float*)d_in[9];
  const float* att_dst= (const float*)d_in[10];
  const float* b_gat  = (const float*)d_in[11];
  const float* gn_w   = (const float*)d_in[12];
  const float* gn_b   = (const float*)d_in[13];
  const float* gn_ms  = (const float*)d_in[14];
  const float* W_gate = (const float*)d_in[15];
  const float* b_gate = (const float*)d_in[16];
  const float* W_head = (const float*)d_in[17];
  const float* b_head = (const float*)d_in[18];
  const float* ln2_g  = (const float*)d_in[19];
  const float* ln2_b  = (const float*)d_in[20];
  const float* W_fc1  = (const float*)d_in[21];
  const float* b_fc1  = (const float*)d_in[22];
  const float* ln3_g  = (const float*)d_in[23];
  const float* ln3_b  = (const float*)d_in[24];
  const float* W_fc2  = (const float*)d_in[25];
  const float* b_fc2  = (const float*)d_in[26];
  float* outp = (float*)d_out;

  const int* srcl = eidx;
  const int* dstl = eidx + EE;

  char* base = (char*)d_ws;
  size_t off = 0;
  auto alloc = [&](size_t bytes)->void*{
    void* p = base + off; off = (off + bytes + 255) & ~(size_t)255; return p;
  };
  float* h    = (float*)alloc((size_t)NN*HD*4);
  float* h1   = (float*)alloc((size_t)NN*HD*4);
  float* y    = (float*)alloc((size_t)NN*HD*4);
  short* xwb  = (short*)alloc((size_t)NN*HD*2);
  float* es   = (float*)alloc((size_t)NN*4);
  float* ed   = (float*)alloc((size_t)NN*4);
  float* shiftv = (float*)alloc(GG*HD*4);
  float* scalev = (float*)alloc(GG*HD*4);
  int* deg       = (int*)alloc((size_t)NN*4);
  int* row_start = (int*)alloc((size_t)(NN+1)*4);
  int* cursor    = (int*)alloc((size_t)NN*4);
  int* csr_src   = (int*)alloc((size_t)EE*4);
  int* blocksum  = (int*)alloc(256*4);
  int* gstart    = (int*)alloc((GG+1)*4);
  short* Wt_fuse = (short*)alloc((size_t)128*KPACK*2);
  short* Wt_gat  = (short*)alloc((size_t)128*128*2);
  short* Wt_gate = (short*)alloc((size_t)128*256*2);
  short* Wt_head = (short*)alloc((size_t)128*128*2);
  short* Wt_fc1  = (short*)alloc((size_t)64*128*2);

  const int NB  = (NN + 255)/256;
  const int GB  = (NN + 127)/128;
  const int EB  = (EE + 255)/256;
  const int WVB = (NN*64 + 255)/256;
  const int WPREP_TOT = 128*KPACK + 128*128 + 128*256 + 128*128 + 64*128;

  wprep_all_kernel<<<(WPREP_TOT+255)/256, 256, 0, stream>>>(
      W_fuse, W_gat, W_gate, W_head, W_fc1,
      Wt_fuse, Wt_gat, Wt_gate, Wt_head, Wt_fc1);

  hipMemsetAsync(deg, 0, (size_t)NN*4, stream);
  hist_gstart_kernel<<<EB, 256, 0, stream>>>(dstl, deg, batch, gstart);
  scan1_kernel<<<NB, 256, 0, stream>>>(deg, row_start, blocksum);
  scan2_kernel<<<1, 256, 0, stream>>>(blocksum, NB);
  scan3_kernel<<<NB, 256, 0, stream>>>(row_start, blocksum, cursor);
  scatter_kernel<<<EB, 256, 0, stream>>>(srcl, dstl, cursor, csr_src);

  // fuse + LN1 + relu -> h, then xw GEMM -> xwb/es/ed (fused, reads rna/ss directly)
  fuse_xw_kernel<<<GB, 512, 0, stream>>>(rna, ss, Wt_fuse, b_fuse, ln1_g, ln1_b,
      Wt_gat, att_src, att_dst, h, xwb, es, ed);

  // ---- GAT layer 1 ----
  gat_aggregate_kernel<<<WVB, 256, 0, stream>>>(xwb, es, ed, row_start, csr_src, b_gat, y);
  gn_group_kernel<<<GG, 1024, 0, stream>>>(y, gstart, gn_w, gn_ms, shiftv, scalev);

  // ---- GAT layer 2 (graphnorm fused into staging, side-writes h1) ----
  mfma_gemm<true><<<GB, 512, 0, stream>>>(y, Wt_gat, gn_b,
      att_src, att_dst, batch, shiftv, scalev, h1, xwb, es, ed, HD, HD);
  gat_aggregate_kernel<<<WVB, 256, 0, stream>>>(xwb, es, ed, row_start, csr_src, b_gat, y);
  gn_group_kernel<<<GG, 1024, 0, stream>>>(y, gstart, gn_w, gn_ms, shiftv, scalev);

  // ---- tail: gate + head + fc1 + fc2 -> out ----
  tail_kernel<<<GB, 512, 0, stream>>>(h1, y, h, batch, shiftv, scalev, gn_b,
      Wt_gate, b_gate, Wt_head, b_head, ln2_g, ln2_b,
      Wt_fc1, b_fc1, ln3_g, ln3_b, W_fc2, b_fc2, outp);
}

// Round 5
// 517.763 us; speedup vs baseline: 1.0909x; 1.0909x over previous
//
#include <hip/hip_runtime.h>
#include <hip/hip_bf16.h>
#include <math.h>

#define NN 50000
#define EE 800000
#define RNA_D 645
#define KFUSE 651
#define KPACK 704
#define HD 128
#define GG 200
#define SAK 72    // LDS k-stride (bf16): 64+8 pad
#define HGS 136   // persistent LDS row stride (bf16)

typedef __attribute__((ext_vector_type(8))) short shortx8;
typedef __attribute__((ext_vector_type(4))) short shortx4;
typedef __attribute__((ext_vector_type(4))) float floatx4;

__device__ __forceinline__ float lrelu(float x){ return x >= 0.f ? x : 0.2f*x; }
__device__ __forceinline__ short f2bf(float x){
  union { __hip_bfloat16 h; short s; } u; u.h = __float2bfloat16(x); return u.s;
}
__device__ __forceinline__ float bf2f(short s){
  union { float f; unsigned u; } c; c.u = ((unsigned)(unsigned short)s) << 16; return c.f;
}
__device__ __forceinline__ float2 upk(unsigned u){
  union { float f; unsigned v; } a, b;
  a.v = u << 16; b.v = u & 0xffff0000u;
  return make_float2(a.f, b.f);
}

// ---------------- graph prep ----------------
__global__ void hist_gstart_kernel(const int* __restrict__ dst, int* __restrict__ deg,
                                   const int* __restrict__ batch, int* __restrict__ gstart){
  int e = blockIdx.x*256 + threadIdx.x;
  if (e < EE) atomicAdd(&deg[dst[e]], 1);
  if (e < NN){
    int g = batch[e];
    if (e == 0){ for (int gg=0; gg<=g; ++gg) gstart[gg] = 0; }
    else { int gp = batch[e-1]; for (int gg=gp+1; gg<=g; ++gg) gstart[gg] = e; }
    if (e == NN-1){ for (int gg=g+1; gg<=GG; ++gg) gstart[gg] = NN; }
  }
}
__global__ void scan1_kernel(const int* __restrict__ deg, int* __restrict__ row_start,
                             int* __restrict__ blocksum){
  __shared__ int s[256];
  int i = blockIdx.x*256 + threadIdx.x;
  int v = (i < NN) ? deg[i] : 0;
  s[threadIdx.x] = v;
  __syncthreads();
  for (int off=1; off<256; off<<=1){
    int t = (threadIdx.x >= off) ? s[threadIdx.x-off] : 0;
    __syncthreads();
    s[threadIdx.x] += t;
    __syncthreads();
  }
  if (i < NN) row_start[i] = s[threadIdx.x] - v;
  if (threadIdx.x == 255) blocksum[blockIdx.x] = s[255];
}
__global__ void scan2_kernel(int* __restrict__ blocksum, int nb){
  __shared__ int s[256];
  int v = (threadIdx.x < nb) ? blocksum[threadIdx.x] : 0;
  s[threadIdx.x] = v;
  __syncthreads();
  for (int off=1; off<256; off<<=1){
    int t = (threadIdx.x >= off) ? s[threadIdx.x-off] : 0;
    __syncthreads();
    s[threadIdx.x] += t;
    __syncthreads();
  }
  blocksum[threadIdx.x] = s[threadIdx.x] - v;
}
__global__ void scan3_kernel(int* __restrict__ row_start, const int* __restrict__ blocksum,
                             int* __restrict__ cursor){
  int i = blockIdx.x*256 + threadIdx.x;
  if (i < NN){
    int v = row_start[i] + blocksum[blockIdx.x];
    row_start[i] = v;
    cursor[i] = v;
  }
  if (i == 0) row_start[NN] = EE;
}
__global__ void scatter_kernel(const int* __restrict__ srcl, const int* __restrict__ dstl,
                               int* __restrict__ cursor, int* __restrict__ csr_src){
  int e = blockIdx.x*256 + threadIdx.x;
  if (e >= EE) return;
  int d = dstl[e];
  int slot = atomicAdd(&cursor[d], 1);
  csr_src[slot] = srcl[e];
}

// ---------------- weight prep ----------------
__global__ void wprep_all_kernel(const float* __restrict__ Wf, const float* __restrict__ Wg,
                                 const float* __restrict__ Wgt, const float* __restrict__ Wh,
                                 const float* __restrict__ W1,
                                 short* __restrict__ Tf, short* __restrict__ Tg,
                                 short* __restrict__ Tgt, short* __restrict__ Th,
                                 short* __restrict__ T1){
  int idx = blockIdx.x*256 + threadIdx.x;
  const int S0=128*KPACK, S1=128*128, S2=128*256, S3=128*128, S4=64*128;
  if (idx < S0){ int n=idx/KPACK, k=idx-n*KPACK; Tf[idx]=f2bf(k<KFUSE ? Wf[k*128+n] : 0.f); return; }
  idx -= S0;
  if (idx < S1){ int n=idx>>7, k=idx&127; Tg[idx]=f2bf(Wg[k*128+n]); return; }
  idx -= S1;
  if (idx < S2){ int n=idx>>8, k=idx&255; Tgt[idx]=f2bf(Wgt[k*128+n]); return; }
  idx -= S2;
  if (idx < S3){ int n=idx>>7, k=idx&127; Th[idx]=f2bf(Wh[k*128+n]); return; }
  idx -= S3;
  if (idx < S4){ int n=idx>>7, k=idx&127; T1[idx]=f2bf(W1[k*64+n]); return; }
}

// ---------------- fused: fuse-GEMM(K=704)+LN+relu -> h, then xw-GEMM(K=128) -> xwb,es,ed
// Phase-1 A-stage: coalesced + batched. Wave w stages rows w*32+i; per row one
// 256B-contiguous load instr (lane=col), all 32 loads batched to regs, then 32 ds_write_b16.
__launch_bounds__(256)
__global__ void fuse_xw_kernel(const float* __restrict__ rna, const float* __restrict__ ss,
                               const short* __restrict__ Wtf, const float* __restrict__ bfu,
                               const float* __restrict__ g1, const float* __restrict__ b1,
                               const short* __restrict__ Wtg,
                               const float* __restrict__ as_, const float* __restrict__ ad_,
                               float* __restrict__ hout, short* __restrict__ xwb,
                               float* __restrict__ es, float* __restrict__ ed){
  __shared__ short sA[128*SAK];
  __shared__ short sB[128*SAK];
  __shared__ short hA[128*HGS];
  const int tid  = threadIdx.x;
  const int wave = tid >> 6, lane = tid & 63;
  const int quad = lane >> 4, l16 = lane & 15;
  const int rowBase = blockIdx.x * 128;
  const int c8  = lane >> 3, k8  = lane & 7;    // B staging

  floatx4 acc[2][8];
  #pragma unroll
  for (int t=0;t<2;++t)
    #pragma unroll
    for (int ct=0;ct<8;++ct)
      #pragma unroll
      for (int j=0;j<4;++j) acc[t][ct][j] = 0.f;

  // ===== phase 1: fuse GEMM K=704 =====
  for (int k0 = 0; k0 < KPACK; k0 += 64){
    // stage A: coalesced (lane=col, 256B/instr) + batched (32 loads then 32 LDS writes)
    {
      float fv[32];
      if (k0 < 640){
        // rows w*32 .. w*32+31 (block rows); guard rows >= NN with a safe clamp
        #pragma unroll
        for (int i=0;i<32;++i){
          int r = wave*32 + i;
          int gr = rowBase + r;
          fv[i] = (gr < NN) ? rna[(size_t)gr*RNA_D + k0 + lane] : 0.f;
        }
      } else {
        #pragma unroll
        for (int i=0;i<32;++i){
          int r = wave*32 + i;
          int gr = rowBase + r;
          int c = k0 + lane;
          float v = 0.f;
          if (gr < NN){
            if (c < RNA_D) v = rna[(size_t)gr*RNA_D + c];
            else if (c < KFUSE) v = ss[gr*6 + (c - RNA_D)];
          }
          fv[i] = v;
        }
      }
      #pragma unroll
      for (int i=0;i<32;++i){
        int r = wave*32 + i;
        sA[r*SAK + lane] = f2bf(fv[i]);
      }
    }
    // stage B
    {
      #pragma unroll
      for (int i=0;i<4;++i){
        int n = wave*32 + i*8 + c8;
        *(shortx8*)&sB[n*SAK + k8*8] = *(const shortx8*)&Wtf[(size_t)n*KPACK + k0 + k8*8];
      }
    }
    __syncthreads();
    #pragma unroll
    for (int ks=0; ks<2; ++ks){
      int kb = ks*32 + quad*8;
      shortx8 af0 = *(const shortx8*)&sA[(wave*32 +      l16)*SAK + kb];
      shortx8 af1 = *(const shortx8*)&sA[(wave*32 + 16 + l16)*SAK + kb];
      #pragma unroll
      for (int ct=0; ct<8; ++ct){
        shortx8 bf = *(const shortx8*)&sB[(ct*16 + l16)*SAK + kb];
        acc[0][ct] = __builtin_amdgcn_mfma_f32_16x16x32_bf16(af0, bf, acc[0][ct], 0,0,0);
        acc[1][ct] = __builtin_amdgcn_mfma_f32_16x16x32_bf16(af1, bf, acc[1][ct], 0,0,0);
      }
    }
    __syncthreads();
  }

  // phase-1 epilogue: +bias, LN(128), relu -> hout (fp32) and hA (bf16)
  {
    float biasv[8], gv[8], bv[8];
    #pragma unroll
    for (int ct=0;ct<8;++ct){
      biasv[ct] = bfu[ct*16+l16]; gv[ct] = g1[ct*16+l16]; bv[ct] = b1[ct*16+l16];
    }
    #pragma unroll
    for (int t=0;t<2;++t)
      #pragma unroll
      for (int i=0;i<4;++i){
        int row = wave*32 + t*16 + quad*4 + i;
        int gr = rowBase + row;
        float v[8]; float s=0.f, q=0.f;
        #pragma unroll
        for (int ct=0;ct<8;++ct){
          v[ct] = acc[t][ct][i] + biasv[ct];
          s += v[ct]; q = fmaf(v[ct], v[ct], q);
        }
        #pragma unroll
        for (int off=1; off<16; off<<=1){ s += __shfl_xor(s,off); q += __shfl_xor(q,off); }
        float mean = s * (1.f/128.f);
        float inv  = rsqrtf(q*(1.f/128.f) - mean*mean + 1e-5f);
        #pragma unroll
        for (int ct=0;ct<8;++ct){
          float o = fmaxf((v[ct]-mean)*inv*gv[ct] + bv[ct], 0.f);
          if (gr < NN) hout[(size_t)gr*HD + ct*16 + l16] = o;
          hA[row*HGS + ct*16 + l16] = f2bf(o);
        }
      }
  }
  __syncthreads();

  // ===== phase 2: xw GEMM K=128, A=hA =====
  floatx4 acc2[2][8];
  #pragma unroll
  for (int t=0;t<2;++t)
    #pragma unroll
    for (int ct=0;ct<8;++ct)
      #pragma unroll
      for (int j=0;j<4;++j) acc2[t][ct][j] = 0.f;

  for (int c2=0; c2<2; ++c2){
    {
      #pragma unroll
      for (int i=0;i<4;++i){
        int n = wave*32 + i*8 + c8;
        *(shortx8*)&sB[n*SAK + k8*8] = *(const shortx8*)&Wtg[(size_t)n*HD + c2*64 + k8*8];
      }
    }
    __syncthreads();
    #pragma unroll
    for (int ks=0; ks<2; ++ks){
      int kg = c2*64 + ks*32 + quad*8;
      int kk = ks*32 + quad*8;
      shortx8 af0 = *(const shortx8*)&hA[(wave*32 +      l16)*HGS + kg];
      shortx8 af1 = *(const shortx8*)&hA[(wave*32 + 16 + l16)*HGS + kg];
      #pragma unroll
      for (int ct=0; ct<8; ++ct){
        shortx8 bf = *(const shortx8*)&sB[(ct*16 + l16)*SAK + kk];
        acc2[0][ct] = __builtin_amdgcn_mfma_f32_16x16x32_bf16(af0, bf, acc2[0][ct], 0,0,0);
        acc2[1][ct] = __builtin_amdgcn_mfma_f32_16x16x32_bf16(af1, bf, acc2[1][ct], 0,0,0);
      }
    }
    __syncthreads();
  }

  // phase-2 epilogue: store xwb bf16 + es/ed
  {
    float asv[8], adv[8];
    #pragma unroll
    for (int ct=0;ct<8;++ct){ asv[ct] = as_[ct*16+l16]; adv[ct] = ad_[ct*16+l16]; }
    #pragma unroll
    for (int t=0;t<2;++t)
      #pragma unroll
      for (int i=0;i<4;++i){
        int gr = rowBase + wave*32 + t*16 + quad*4 + i;
        float s=0.f, d=0.f;
        #pragma unroll
        for (int ct=0;ct<8;++ct){
          float v = acc2[t][ct][i];
          s = fmaf(v, asv[ct], s); d = fmaf(v, adv[ct], d);
          if (gr < NN) xwb[(size_t)gr*HD + ct*16 + l16] = f2bf(v);
        }
        #pragma unroll
        for (int off=1; off<16; off<<=1){ s += __shfl_xor(s,off); d += __shfl_xor(d,off); }
        if (l16 == 0 && gr < NN){ es[gr] = s; ed[gr] = d; }
      }
  }
}

// ---------------- MFMA GEMM (layer-2 xw with fused graphnorm A-staging) ----------------
template<int NT, bool GNA>
__launch_bounds__(256)
__global__ void mfma_gemm(const float* __restrict__ A0,
                          const short* __restrict__ Wt,
                          const float* __restrict__ gb,
                          const float* __restrict__ as_, const float* __restrict__ ad_,
                          const int* __restrict__ batch, const float* __restrict__ gnsh,
                          const float* __restrict__ gnsc, float* __restrict__ side,
                          short* __restrict__ outb,
                          float* __restrict__ es, float* __restrict__ ed,
                          int K, int Kp){
  __shared__ short sA[128*SAK];
  __shared__ short sB[NT*16*SAK];
  const int tid  = threadIdx.x;
  const int wave = tid >> 6, lane = tid & 63;
  const int quad = lane >> 4, l16 = lane & 15;
  const int rowBase = blockIdx.x * 128;
  const int r16 = lane >> 4, c16 = lane & 15;
  const int c8  = lane >> 3, k8  = lane & 7;

  floatx4 acc[2][NT];
  #pragma unroll
  for (int t=0;t<2;++t)
    #pragma unroll
    for (int ct=0;ct<NT;++ct)
      #pragma unroll
      for (int j=0;j<4;++j) acc[t][ct][j] = 0.f;

  for (int k0 = 0; k0 < K; k0 += 64){
    // ---- stage A: batched float4 (HD rows 16B-aligned) ----
    {
      float4 fv[8];
      #pragma unroll
      for (int i=0;i<8;++i){
        int gr = rowBase + wave*32 + i*4 + r16;
        fv[i] = (gr < NN) ? *(const float4*)&A0[(size_t)gr*HD + k0 + c16*4]
                          : make_float4(0.f,0.f,0.f,0.f);
      }
      if (GNA){
        #pragma unroll
        for (int i=0;i<8;++i){
          int gr = rowBase + wave*32 + i*4 + r16;
          if (gr < NN){
            int g = batch[gr];
            int cb = k0 + c16*4;
            float4 sh = *(const float4*)&gnsh[g*HD + cb];
            float4 sc = *(const float4*)&gnsc[g*HD + cb];
            float4 bb = *(const float4*)&gb[cb];
            float4 v;
            v.x = fmaxf((fv[i].x - sh.x)*sc.x + bb.x, 0.f);
            v.y = fmaxf((fv[i].y - sh.y)*sc.y + bb.y, 0.f);
            v.z = fmaxf((fv[i].z - sh.z)*sc.z + bb.z, 0.f);
            v.w = fmaxf((fv[i].w - sh.w)*sc.w + bb.w, 0.f);
            *(float4*)&side[(size_t)gr*HD + cb] = v;
            fv[i] = v;
          }
        }
      }
      #pragma unroll
      for (int i=0;i<8;++i){
        int r = wave*32 + i*4 + r16;
        shortx4 t;
        t[0]=f2bf(fv[i].x); t[1]=f2bf(fv[i].y); t[2]=f2bf(fv[i].z); t[3]=f2bf(fv[i].w);
        *(shortx4*)&sA[r*SAK + c16*4] = t;
      }
    }
    // ---- stage B ----
    {
      #pragma unroll
      for (int i=0;i<NT/2;++i){
        int n = wave*(NT*4) + i*8 + c8;
        *(shortx8*)&sB[n*SAK + k8*8] = *(const shortx8*)&Wt[(size_t)n*Kp + k0 + k8*8];
      }
    }
    __syncthreads();
    // ---- MFMA ----
    #pragma unroll
    for (int ks=0; ks<2; ++ks){
      int kb = ks*32 + quad*8;
      shortx8 af0 = *(const shortx8*)&sA[(wave*32 +      l16)*SAK + kb];
      shortx8 af1 = *(const shortx8*)&sA[(wave*32 + 16 + l16)*SAK + kb];
      #pragma unroll
      for (int ct=0; ct<NT; ++ct){
        shortx8 bf = *(const shortx8*)&sB[(ct*16 + l16)*SAK + kb];
        acc[0][ct] = __builtin_amdgcn_mfma_f32_16x16x32_bf16(af0, bf, acc[0][ct], 0,0,0);
        acc[1][ct] = __builtin_amdgcn_mfma_f32_16x16x32_bf16(af1, bf, acc[1][ct], 0,0,0);
      }
    }
    __syncthreads();
  }

  // ---- epilogue: xw + es/ed ----
  {
    float asv[NT], adv[NT];
    #pragma unroll
    for (int ct=0;ct<NT;++ct){ asv[ct] = as_[ct*16+l16]; adv[ct] = ad_[ct*16+l16]; }
    #pragma unroll
    for (int t=0;t<2;++t)
      #pragma unroll
      for (int i=0;i<4;++i){
        int gr = rowBase + wave*32 + t*16 + quad*4 + i;
        float s=0.f, d=0.f;
        #pragma unroll
        for (int ct=0;ct<NT;++ct){
          float v = acc[t][ct][i];
          s = fmaf(v, asv[ct], s); d = fmaf(v, adv[ct], d);
          if (gr < NN) outb[(size_t)gr*HD + ct*16 + l16] = f2bf(v);
        }
        #pragma unroll
        for (int off=1; off<16; off<<=1){ s += __shfl_xor(s,off); d += __shfl_xor(d,off); }
        if (l16 == 0 && gr < NN){ es[gr] = s; ed[gr] = d; }
      }
  }
}

// ---------------- GAT aggregation: bf16 gather ----------------
__launch_bounds__(256)
__global__ void gat_aggregate_kernel(const short* __restrict__ xwb, const float* __restrict__ es,
                                     const float* __restrict__ ed, const int* __restrict__ row_start,
                                     const int* __restrict__ csr_src, const float* __restrict__ bgat,
                                     float* __restrict__ out){
  int gid = blockIdx.x*256 + threadIdx.x;
  int n = gid >> 6, lane = gid & 63;
  if (n >= NN) return;
  int beg = row_start[n], end = row_start[n+1];
  float edn = ed[n];
  float sc_self = lrelu(es[n] + edn);

  int i0 = beg + lane;
  bool v0 = i0 < end;
  int sA = v0 ? csr_src[i0] : 0;
  float eA = v0 ? lrelu(es[sA] + edn) : -3.0e38f;
  float m = fmaxf(sc_self, eA);
  for (int i = beg + 64 + lane; i < end; i += 64)
    m = fmaxf(m, lrelu(es[csr_src[i]] + edn));
  #pragma unroll
  for (int off=1; off<64; off<<=1) m = fmaxf(m, __shfl_xor(m, off));

  float wA = v0 ? __expf(eA - m) : 0.f;
  float wsum_l = wA;
  float wself = __expf(sc_self - m);
  float2 self2 = upk(*(const unsigned*)&xwb[(size_t)n*HD + 2*lane]);
  float a0 = wself*self2.x, a1 = wself*self2.y;

  int deg0 = min(end - beg, 64);
  int j = 0;
  for (; j + 8 <= deg0; j += 8){
    int ss[8]; float ww[8]; unsigned xv[8];
    #pragma unroll
    for (int u=0;u<8;++u){ ss[u]=__shfl(sA,j+u); ww[u]=__shfl(wA,j+u); }
    #pragma unroll
    for (int u=0;u<8;++u) xv[u] = *(const unsigned*)&xwb[(size_t)ss[u]*HD + 2*lane];
    #pragma unroll
    for (int u=0;u<8;++u){ float2 f=upk(xv[u]); a0=fmaf(ww[u],f.x,a0); a1=fmaf(ww[u],f.y,a1); }
  }
  for (; j < deg0; ++j){
    int s=__shfl(sA,j); float w=__shfl(wA,j);
    float2 f = upk(*(const unsigned*)&xwb[(size_t)s*HD + 2*lane]);
    a0=fmaf(w,f.x,a0); a1=fmaf(w,f.y,a1);
  }
  for (int c = beg + 64; c < end; c += 64){
    int i = c + lane;
    bool vb = i < end;
    int sB = vb ? csr_src[i] : 0;
    float wB = vb ? __expf(lrelu(es[sB] + edn) - m) : 0.f;
    wsum_l += wB;
    int degc = min(end - c, 64);
    for (int jj=0; jj<degc; ++jj){
      int s=__shfl(sB,jj); float w=__shfl(wB,jj);
      float2 f = upk(*(const unsigned*)&xwb[(size_t)s*HD + 2*lane]);
      a0=fmaf(w,f.x,a0); a1=fmaf(w,f.y,a1);
    }
  }
  #pragma unroll
  for (int off=1; off<64; off<<=1) wsum_l += __shfl_xor(wsum_l, off);
  float dinv = 1.f/(wsum_l + wself + 1e-16f);
  float2 b2 = *(const float2*)&bgat[2*lane];
  float2 o; o.x = a0*dinv + b2.x; o.y = a1*dinv + b2.y;
  *(float2*)&out[(size_t)n*HD + 2*lane] = o;
}

// ---------------- GraphNorm group stats ----------------
__launch_bounds__(1024)
__global__ void gn_group_kernel(const float* __restrict__ x, const int* __restrict__ gstart,
                                const float* __restrict__ gnw, const float* __restrict__ gnms,
                                float* __restrict__ shiftv, float* __restrict__ scalev){
  int g = blockIdx.x;
  int n0 = gstart[g], n1 = gstart[g+1];
  int f = threadIdx.x & 127, slot = threadIdx.x >> 7;   // 0..7
  float s = 0.f, q = 0.f;
  for (int n = n0 + slot; n < n1; n += 8){
    float v = x[(size_t)n*HD + f];
    s += v; q = fmaf(v, v, q);
  }
  __shared__ float rs[1024], rq[1024];
  rs[threadIdx.x] = s; rq[threadIdx.x] = q;
  __syncthreads();
  if (threadIdx.x < 512){ rs[threadIdx.x] += rs[threadIdx.x+512]; rq[threadIdx.x] += rq[threadIdx.x+512]; }
  __syncthreads();
  if (threadIdx.x < 256){ rs[threadIdx.x] += rs[threadIdx.x+256]; rq[threadIdx.x] += rq[threadIdx.x+256]; }
  __syncthreads();
  if (threadIdx.x < 128){
    s = rs[threadIdx.x] + rs[threadIdx.x+128];
    q = rq[threadIdx.x] + rq[threadIdx.x+128];
    float c = fmaxf((float)(n1 - n0), 1.f);
    float mean = s / c;
    float ms = gnms[f];
    float var = q/c - mean*mean*ms*(2.f - ms);
    shiftv[g*HD+f] = ms*mean;
    scalev[g*HD+f] = gnw[f] / sqrtf(var + 1e-5f);
  }
}

// ---------------- tail: gate + head(+LN2) + fc1(+LN3) + fc2 ----------------
__launch_bounds__(256)
__global__ void tail_kernel(const float* __restrict__ h1, const float* __restrict__ y2,
                            const float* __restrict__ hres, const int* __restrict__ batch,
                            const float* __restrict__ gnsh, const float* __restrict__ gnsc,
                            const float* __restrict__ gnb,
                            const short* __restrict__ Wt_gate, const float* __restrict__ b_gate,
                            const short* __restrict__ Wt_head, const float* __restrict__ b_head,
                            const float* __restrict__ ln2g, const float* __restrict__ ln2b,
                            const short* __restrict__ Wt_fc1, const float* __restrict__ b_fc1,
                            const float* __restrict__ ln3g, const float* __restrict__ ln3b,
                            const float* __restrict__ W_fc2, const float* __restrict__ b_fc2,
                            float* __restrict__ outp){
  __shared__ short hgL[128*HGS];   // persistent: h2 -> hg -> t1
  __shared__ short sA[128*SAK];
  __shared__ short sB[128*SAK];
  const int tid = threadIdx.x, wave = tid>>6, lane = tid&63;
  const int quad = lane>>4, l16 = lane&15;
  const int rowBase = blockIdx.x*128;
  const int r16 = lane >> 4, c16 = lane & 15;
  const int c8  = lane >> 3, k8  = lane & 7;

  // ===== stage 1: gate GEMM, K=256 (A = [h1 | h2=gn(y2)+hres]) =====
  floatx4 acc[2][8];
  #pragma unroll
  for (int t=0;t<2;++t)
    #pragma unroll
    for (int ct=0;ct<8;++ct)
      #pragma unroll
      for (int j=0;j<4;++j) acc[t][ct][j]=0.f;

  for (int c2=0; c2<4; ++c2){
    int kb = c2*64;
    if (kb < 128){
      float4 fv[8];
      #pragma unroll
      for (int i=0;i<8;++i){
        int gr = rowBase + wave*32 + i*4 + r16;
        fv[i] = (gr < NN) ? *(const float4*)&h1[(size_t)gr*HD + kb + c16*4]
                          : make_float4(0.f,0.f,0.f,0.f);
      }
      #pragma unroll
      for (int i=0;i<8;++i){
        int r = wave*32 + i*4 + r16;
        shortx4 t;
        t[0]=f2bf(fv[i].x); t[1]=f2bf(fv[i].y); t[2]=f2bf(fv[i].z); t[3]=f2bf(fv[i].w);
        *(shortx4*)&sA[r*SAK + c16*4] = t;
      }
    } else {
      int cb = kb - 128 + c16*4;
      float4 fv[8];
      #pragma unroll
      for (int i=0;i<8;++i){
        int gr = rowBase + wave*32 + i*4 + r16;
        if (gr < NN){
          int g = batch[gr];
          float4 yv = *(const float4*)&y2[(size_t)gr*HD + cb];
          float4 hv = *(const float4*)&hres[(size_t)gr*HD + cb];
          float4 sh = *(const float4*)&gnsh[g*HD + cb];
          float4 sc = *(const float4*)&gnsc[g*HD + cb];
          float4 bb = *(const float4*)&gnb[cb];
          float4 v;
          v.x = fmaxf((yv.x - sh.x)*sc.x + bb.x, 0.f) + hv.x;
          v.y = fmaxf((yv.y - sh.y)*sc.y + bb.y, 0.f) + hv.y;
          v.z = fmaxf((yv.z - sh.z)*sc.z + bb.z, 0.f) + hv.z;
          v.w = fmaxf((yv.w - sh.w)*sc.w + bb.w, 0.f) + hv.w;
          fv[i] = v;
        } else {
          fv[i] = make_float4(0.f,0.f,0.f,0.f);
        }
      }
      #pragma unroll
      for (int i=0;i<8;++i){
        int r = wave*32 + i*4 + r16;
        shortx4 t;
        t[0]=f2bf(fv[i].x); t[1]=f2bf(fv[i].y); t[2]=f2bf(fv[i].z); t[3]=f2bf(fv[i].w);
        *(shortx4*)&hgL[r*HGS + cb] = t;   // persist h2
        *(shortx4*)&sA[r*SAK + c16*4] = t;
      }
    }
    // stage B (Wt_gate: [128][256])
    {
      #pragma unroll
      for (int i=0;i<4;++i){
        int n = wave*32 + i*8 + c8;
        *(shortx8*)&sB[n*SAK + k8*8] = *(const shortx8*)&Wt_gate[(size_t)n*256 + kb + k8*8];
      }
    }
    __syncthreads();
    #pragma unroll
    for (int ks=0; ks<2; ++ks){
      int kk = ks*32 + quad*8;
      shortx8 af0 = *(const shortx8*)&sA[(wave*32 +      l16)*SAK + kk];
      shortx8 af1 = *(const shortx8*)&sA[(wave*32 + 16 + l16)*SAK + kk];
      #pragma unroll
      for (int ct=0; ct<8; ++ct){
        shortx8 bf = *(const shortx8*)&sB[(ct*16 + l16)*SAK + kk];
        acc[0][ct] = __builtin_amdgcn_mfma_f32_16x16x32_bf16(af0, bf, acc[0][ct], 0,0,0);
        acc[1][ct] = __builtin_amdgcn_mfma_f32_16x16x32_bf16(af1, bf, acc[1][ct], 0,0,0);
      }
    }
    __syncthreads();
  }
  // gate epilogue: hg = g*h1 + (1-g)*h2  -> hgL
  {
    float biasv[8];
    #pragma unroll
    for (int ct=0;ct<8;++ct) biasv[ct] = b_gate[ct*16+l16];
    #pragma unroll
    for (int t=0;t<2;++t)
      #pragma unroll
      for (int i=0;i<4;++i){
        int row = wave*32 + t*16 + quad*4 + i;
        int gr = rowBase + row;
        #pragma unroll
        for (int ct=0;ct<8;++ct){
          int c = ct*16 + l16;
          float g = 1.f/(1.f + __expf(-(acc[t][ct][i] + biasv[ct])));
          float x1 = (gr < NN) ? h1[(size_t)gr*HD + c] : 0.f;
          float x2 = bf2f(hgL[row*HGS + c]);
          hgL[row*HGS + c] = f2bf(g*x1 + (1.f-g)*x2);
        }
      }
  }
  __syncthreads();

  // ===== stage 2: head GEMM K=128, A=hgL, +bias LN(128) relu -> hgL =====
  floatx4 acc2[2][8];
  #pragma unroll
  for (int t=0;t<2;++t)
    #pragma unroll
    for (int ct=0;ct<8;++ct)
      #pragma unroll
      for (int j=0;j<4;++j) acc2[t][ct][j]=0.f;
  for (int c2=0;c2<2;++c2){
    {
      #pragma unroll
      for (int i=0;i<4;++i){
        int n = wave*32 + i*8 + c8;
        *(shortx8*)&sB[n*SAK + k8*8] = *(const shortx8*)&Wt_head[(size_t)n*128 + c2*64 + k8*8];
      }
    }
    __syncthreads();
    #pragma unroll
    for (int ks=0; ks<2; ++ks){
      int kg = c2*64 + ks*32 + quad*8;
      int kk = ks*32 + quad*8;
      shortx8 af0 = *(const shortx8*)&hgL[(wave*32 +      l16)*HGS + kg];
      shortx8 af1 = *(const shortx8*)&hgL[(wave*32 + 16 + l16)*HGS + kg];
      #pragma unroll
      for (int ct=0; ct<8; ++ct){
        shortx8 bf = *(const shortx8*)&sB[(ct*16 + l16)*SAK + kk];
        acc2[0][ct] = __builtin_amdgcn_mfma_f32_16x16x32_bf16(af0, bf, acc2[0][ct], 0,0,0);
        acc2[1][ct] = __builtin_amdgcn_mfma_f32_16x16x32_bf16(af1, bf, acc2[1][ct], 0,0,0);
      }
    }
    __syncthreads();
  }
  // head epilogue: LN(128) relu -> hgL (t1, bf16)
  {
    float biasv[8], gv[8], bv[8];
    #pragma unroll
    for (int ct=0;ct<8;++ct){
      biasv[ct] = b_head[ct*16+l16]; gv[ct] = ln2g[ct*16+l16]; bv[ct] = ln2b[ct*16+l16];
    }
    #pragma unroll
    for (int t=0;t<2;++t)
      #pragma unroll
      for (int i=0;i<4;++i){
        int row = wave*32 + t*16 + quad*4 + i;
        float v[8]; float s=0.f, q=0.f;
        #pragma unroll
        for (int ct=0;ct<8;++ct){
          v[ct] = acc2[t][ct][i] + biasv[ct];
          s += v[ct]; q = fmaf(v[ct], v[ct], q);
        }
        #pragma unroll
        for (int off=1; off<16; off<<=1){ s += __shfl_xor(s,off); q += __shfl_xor(q,off); }
        float mean = s * (1.f/128.f);
        float inv  = rsqrtf(q*(1.f/128.f) - mean*mean + 1e-5f);
        #pragma unroll
        for (int ct=0;ct<8;++ct)
          hgL[row*HGS + ct*16 + l16] = f2bf(fmaxf((v[ct]-mean)*inv*gv[ct] + bv[ct], 0.f));
      }
  }
  __syncthreads();

  // ===== stage 3: fc1 K=128 -> 64 cols, LN(64), relu, dot W_fc2 -> outp =====
  floatx4 acc3[2][4];
  #pragma unroll
  for (int t=0;t<2;++t)
    #pragma unroll
    for (int ct=0;ct<4;++ct)
      #pragma unroll
      for (int j=0;j<4;++j) acc3[t][ct][j]=0.f;
  for (int c2=0;c2<2;++c2){
    {
      #pragma unroll
      for (int i=0;i<2;++i){
        int n = wave*16 + i*8 + c8;
        *(shortx8*)&sB[n*SAK + k8*8] = *(const shortx8*)&Wt_fc1[(size_t)n*128 + c2*64 + k8*8];
      }
    }
    __syncthreads();
    #pragma unroll
    for (int ks=0; ks<2; ++ks){
      int kg = c2*64 + ks*32 + quad*8;
      int kk = ks*32 + quad*8;
      shortx8 af0 = *(const shortx8*)&hgL[(wave*32 +      l16)*HGS + kg];
      shortx8 af1 = *(const shortx8*)&hgL[(wave*32 + 16 + l16)*HGS + kg];
      #pragma unroll
      for (int ct=0; ct<4; ++ct){
        shortx8 bf = *(const shortx8*)&sB[(ct*16 + l16)*SAK + kk];
        acc3[0][ct] = __builtin_amdgcn_mfma_f32_16x16x32_bf16(af0, bf, acc3[0][ct], 0,0,0);
        acc3[1][ct] = __builtin_amdgcn_mfma_f32_16x16x32_bf16(af1, bf, acc3[1][ct], 0,0,0);
      }
    }
    __syncthreads();
  }
  {
    float biasv[4], gv[4], bv[4], w2v[4];
    #pragma unroll
    for (int ct=0;ct<4;++ct){
      biasv[ct] = b_fc1[ct*16+l16]; gv[ct] = ln3g[ct*16+l16]; bv[ct] = ln3b[ct*16+l16];
      w2v[ct] = W_fc2[ct*16+l16];
    }
    float b2 = b_fc2[0];
    #pragma unroll
    for (int t=0;t<2;++t)
      #pragma unroll
      for (int i=0;i<4;++i){
        int gr = rowBase + wave*32 + t*16 + quad*4 + i;
        float v[4]; float s=0.f, q=0.f;
        #pragma unroll
        for (int ct=0;ct<4;++ct){
          v[ct] = acc3[t][ct][i] + biasv[ct];
          s += v[ct]; q = fmaf(v[ct], v[ct], q);
        }
        #pragma unroll
        for (int off=1; off<16; off<<=1){ s += __shfl_xor(s,off); q += __shfl_xor(q,off); }
        float mean = s * (1.f/64.f);
        float inv  = rsqrtf(q*(1.f/64.f) - mean*mean + 1e-5f);
        float p = 0.f;
        #pragma unroll
        for (int ct=0;ct<4;++ct){
          float o = fmaxf((v[ct]-mean)*inv*gv[ct] + bv[ct], 0.f);
          p = fmaf(o, w2v[ct], p);
        }
        #pragma unroll
        for (int off=1; off<16; off<<=1) p += __shfl_xor(p, off);
        if (l16 == 0 && gr < NN) outp[gr] = p + b2;
      }
  }
}

// ---------------- launch ----------------
extern "C" void kernel_launch(void* const* d_in, const int* in_sizes, int n_in,
                              void* d_out, int out_size, void* d_ws, size_t ws_size,
                              hipStream_t stream){
  const float* rna    = (const float*)d_in[0];
  const float* ss     = (const float*)d_in[1];
  const int*   eidx   = (const int*)d_in[2];
  const int*   batch  = (const int*)d_in[3];
  const float* W_fuse = (const float*)d_in[4];
  const float* b_fuse = (const float*)d_in[5];
  const float* ln1_g  = (const float*)d_in[6];
  const float* ln1_b  = (const float*)d_in[7];
  const float* W_gat  = (const float*)d_in[8];
  const float* att_src= (const float*)d_in[9];
  const float* att_dst= (const float*)d_in[10];
  const float* b_gat  = (const float*)d_in[11];
  const float* gn_w   = (const float*)d_in[12];
  const float* gn_b   = (const float*)d_in[13];
  const float* gn_ms  = (const float*)d_in[14];
  const float* W_gate = (const float*)d_in[15];
  const float* b_gate = (const float*)d_in[16];
  const float* W_head = (const float*)d_in[17];
  const float* b_head = (const float*)d_in[18];
  const float* ln2_g  = (const float*)d_in[19];
  const float* ln2_b  = (const float*)d_in[20];
  const float* W_fc1  = (const float*)d_in[21];
  const float* b_fc1  = (const float*)d_in[22];
  const float* ln3_g  = (const float*)d_in[23];
  const float* ln3_b  = (const float*)d_in[24];
  const float* W_fc2  = (const float*)d_in[25];
  const float* b_fc2  = (const float*)d_in[26];
  float* outp = (float*)d_out;

  const int* srcl = eidx;
  const int* dstl = eidx + EE;

  char* base = (char*)d_ws;
  size_t off = 0;
  auto alloc = [&](size_t bytes)->void*{
    void* p = base + off; off = (off + bytes + 255) & ~(size_t)255; return p;
  };
  float* h    = (float*)alloc((size_t)NN*HD*4);
  float* h1   = (float*)alloc((size_t)NN*HD*4);
  float* y    = (float*)alloc((size_t)NN*HD*4);
  short* xwb  = (short*)alloc((size_t)NN*HD*2);
  float* es   = (float*)alloc((size_t)NN*4);
  float* ed   = (float*)alloc((size_t)NN*4);
  float* shiftv = (float*)alloc(GG*HD*4);
  float* scalev = (float*)alloc(GG*HD*4);
  int* deg       = (int*)alloc((size_t)NN*4);
  int* row_start = (int*)alloc((size_t)(NN+1)*4);
  int* cursor    = (int*)alloc((size_t)NN*4);
  int* csr_src   = (int*)alloc((size_t)EE*4);
  int* blocksum  = (int*)alloc(256*4);
  int* gstart    = (int*)alloc((GG+1)*4);
  short* Wt_fuse = (short*)alloc((size_t)128*KPACK*2);
  short* Wt_gat  = (short*)alloc((size_t)128*128*2);
  short* Wt_gate = (short*)alloc((size_t)128*256*2);
  short* Wt_head = (short*)alloc((size_t)128*128*2);
  short* Wt_fc1  = (short*)alloc((size_t)64*128*2);

  const int NB  = (NN + 255)/256;
  const int GB  = (NN + 127)/128;
  const int EB  = (EE + 255)/256;
  const int WVB = (NN*64 + 255)/256;
  const int WPREP_TOT = 128*KPACK + 128*128 + 128*256 + 128*128 + 64*128;

  wprep_all_kernel<<<(WPREP_TOT+255)/256, 256, 0, stream>>>(
      W_fuse, W_gat, W_gate, W_head, W_fc1,
      Wt_fuse, Wt_gat, Wt_gate, Wt_head, Wt_fc1);

  hipMemsetAsync(deg, 0, (size_t)NN*4, stream);
  hist_gstart_kernel<<<EB, 256, 0, stream>>>(dstl, deg, batch, gstart);
  scan1_kernel<<<NB, 256, 0, stream>>>(deg, row_start, blocksum);
  scan2_kernel<<<1, 256, 0, stream>>>(blocksum, NB);
  scan3_kernel<<<NB, 256, 0, stream>>>(row_start, blocksum, cursor);
  scatter_kernel<<<EB, 256, 0, stream>>>(srcl, dstl, cursor, csr_src);

  // fuse + LN1 + relu -> h, then xw GEMM -> xwb/es/ed (fused, reads rna/ss directly)
  fuse_xw_kernel<<<GB, 256, 0, stream>>>(rna, ss, Wt_fuse, b_fuse, ln1_g, ln1_b,
      Wt_gat, att_src, att_dst, h, xwb, es, ed);

  // ---- GAT layer 1 ----
  gat_aggregate_kernel<<<WVB, 256, 0, stream>>>(xwb, es, ed, row_start, csr_src, b_gat, y);
  gn_group_kernel<<<GG, 1024, 0, stream>>>(y, gstart, gn_w, gn_ms, shiftv, scalev);

  // ---- GAT layer 2 (graphnorm fused into staging, side-writes h1) ----
  mfma_gemm<8,true><<<GB, 256, 0, stream>>>(y, Wt_gat, gn_b,
      att_src, att_dst, batch, shiftv, scalev, h1, xwb, es, ed, HD, HD);
  gat_aggregate_kernel<<<WVB, 256, 0, stream>>>(xwb, es, ed, row_start, csr_src, b_gat, y);
  gn_group_kernel<<<GG, 1024, 0, stream>>>(y, gstart, gn_w, gn_ms, shiftv, scalev);

  // ---- tail: gate + head + fc1 + fc2 -> out ----
  tail_kernel<<<GB, 256, 0, stream>>>(h1, y, h, batch, shiftv, scalev, gn_b,
      Wt_gate, b_gate, Wt_head, b_head, ln2_g, ln2_b,
      Wt_fc1, b_fc1, ln3_g, ln3_b, W_fc2, b_fc2, outp);
}